// Round 16
// baseline (603.466 us; speedup 1.0000x reference)
//
#include <hip/hip_runtime.h>
#include <hip/hip_fp16.h>

#define N_NODES_C 100000
#define N_EDGES_C 3200000
#define IN_F_C 10
#define HID_C 64
#define N_CLS_C 10
#define NEG_SLOPE_C 0.01f

#define NBUCK 98        // ceil(100000/1024); bucket = dst >> 10
#define BCAP  36864     // mean 32768, sigma ~180 -> +22 sigma headroom
#define TILE  2048      // edges per block in k_bucket
#define PL_H2 (N_NODES_C * 16)   // half2 elements per feature-plane

typedef _Float16 f16x2 __attribute__((ext_vector_type(2)));

__device__ __forceinline__ float fdot2(unsigned int a, unsigned int b, float c) {
#if defined(__has_builtin) && __has_builtin(__builtin_amdgcn_fdot2)
    return __builtin_amdgcn_fdot2(__builtin_bit_cast(f16x2, a), __builtin_bit_cast(f16x2, b), c, false);
#else
    __half2 ah = __builtin_bit_cast(__half2, a), bh = __builtin_bit_cast(__half2, b);
    float2 af = __half22float2(ah), bf = __half22float2(bh);
    return c + af.x * bf.x + af.y * bf.y;
#endif
}

// ---------------- combined prepack + bcur zero (replaces 3 kernels + memset) ----------------
__global__ __launch_bounds__(256) void k_prep(const float* __restrict__ W2, const float* __restrict__ W3,
                                              const float* __restrict__ Wfc,
                                              uint4* __restrict__ wh2, uint4* __restrict__ wh3,
                                              float2* __restrict__ wf2, int* __restrict__ bcur) {
    const int b = blockIdx.x, t = threadIdx.x;
    if (b < 2) {
        const float* W = b ? W3 : W2;
        uint4* wh = b ? wh3 : wh2;
        for (int i = t; i < 8 * HID_C; i += 256) {
            int k8 = i >> 6, f = i & 63;
            __half2 h[4];
#pragma unroll
            for (int j = 0; j < 4; ++j)
                h[j] = __floats2half2_rn(W[(8 * k8 + 2 * j) * HID_C + f],
                                         W[(8 * k8 + 2 * j + 1) * HID_C + f]);
            wh[i] = *(uint4*)h;
        }
    } else if (b == 2) {
        for (int i = t; i < 32 * N_CLS_C; i += 256) {
            int k2 = i / N_CLS_C, c = i - k2 * N_CLS_C;
            wf2[i] = make_float2(Wfc[(2 * k2) * N_CLS_C + c], Wfc[(2 * k2 + 1) * N_CLS_C + c]);
        }
    } else {
        if (t < 128) bcur[t] = 0;
    }
}

// ---------------- pass 1: bucket partition (proven) ----------------
__global__ __launch_bounds__(256) void k_bucket(const int* __restrict__ src,
                                                const int* __restrict__ dst,
                                                int* __restrict__ bcur,
                                                int* __restrict__ pairs, int E) {
    __shared__ int lcnt[NBUCK];
    __shared__ int gbase[NBUCK];
    const int t = threadIdx.x;
    for (int i = t; i < NBUCK; i += 256) lcnt[i] = 0;
    __syncthreads();
    const int base = blockIdx.x * TILE;
    int p[8], r[8], nb[8];
#pragma unroll
    for (int i = 0; i < 8; ++i) {
        int e = base + t + i * 256;
        if (e < E) {
            int s = src[e], d = dst[e];
            int b = d >> 10;
            nb[i] = b;
            p[i] = (s << 10) | (d & 1023);
            r[i] = atomicAdd(&lcnt[b], 1);
        }
    }
    __syncthreads();
    for (int i = t; i < NBUCK; i += 256)
        gbase[i] = lcnt[i] ? atomicAdd(&bcur[i], lcnt[i]) : 0;
    __syncthreads();
#pragma unroll
    for (int i = 0; i < 8; ++i) {
        int e = base + t + i * 256;
        if (e < E) {
            int pos = gbase[nb[i]] + r[i];
            if (pos < BCAP) pairs[nb[i] * BCAP + pos] = p[i];
        }
    }
}

// ---------------- pass 2: per-bucket hist + scan + row_ptr/dinv + placement; bucket-prefix fused ----------------
__global__ __launch_bounds__(1024) void k_build(const int* __restrict__ pairs,
                                                const int* __restrict__ bcur,
                                                int* __restrict__ row_ptr,
                                                float* __restrict__ dinv,
                                                int* __restrict__ col) {
    __shared__ int hist[1024];
    __shared__ int sm[1024];
    __shared__ int bs[128];
    const int b = blockIdx.x;
    const int t = threadIdx.x;
    const int n = min(bcur[b], BCAP);
    const int* pp = pairs + b * BCAP;

    if (t < 128) bs[t] = (t < NBUCK) ? bcur[t] : 0;
    __syncthreads();
    for (int off = 1; off < 128; off <<= 1) {
        int u = 0;
        if (t < 128 && t >= off) u = bs[t - off];
        __syncthreads();
        if (t < 128) bs[t] += u;
        __syncthreads();
    }
    const int base = (b > 0) ? bs[b - 1] : 0;

    hist[t] = 0;
    __syncthreads();
    for (int i = t; i < n; i += 1024) atomicAdd(&hist[pp[i] & 1023], 1);
    __syncthreads();
    int c = hist[t];
    sm[t] = c;
    __syncthreads();
    for (int off = 1; off < 1024; off <<= 1) {
        int u = (t >= off) ? sm[t - off] : 0;
        __syncthreads();
        sm[t] += u;
        __syncthreads();
    }
    int rp = base + sm[t] - c;
    int gnode = (b << 10) + t;
    if (gnode < N_NODES_C) {
        row_ptr[gnode] = rp;
        dinv[gnode] = rsqrtf((float)(c + 1));
        if (gnode == N_NODES_C - 1) row_ptr[N_NODES_C] = rp + c;
    }
    __syncthreads();
    sm[t] = rp;
    __syncthreads();
    for (int i = t; i < n; i += 1024) {
        int p = pp[i];
        int idx = atomicAdd(&sm[p & 1023], 1);
        col[idx] = p >> 10;
    }
}

// ---------------- layer-1 transform: hs = (x @ W1) * dinv, plane-split output ----------------
__global__ __launch_bounds__(256) void k_mm0(const float* __restrict__ x,
                                             const float* __restrict__ W,
                                             const float* __restrict__ dinv,
                                             __half2* __restrict__ hs, int n) {
    __shared__ float4 W4[IN_F_C * 16];
    const int t = threadIdx.x;
    for (int i = t; i < IN_F_C * 16; i += 256) {
        int k = i >> 4, f4 = i & 15;
        W4[i] = ((const float4*)(W + k * HID_C))[f4];
    }
    __syncthreads();
    int idx = blockIdx.x * 256 + t;
    if (idx >= n * 16) return;
    int nn = idx >> 4, f4 = idx & 15;
    const float* row = x + nn * IN_F_C;
    float4 acc = make_float4(0.f, 0.f, 0.f, 0.f);
#pragma unroll
    for (int k = 0; k < IN_F_C; ++k) {
        float xv = row[k];
        float4 w = W4[k * 16 + f4];
        acc.x += xv * w.x; acc.y += xv * w.y; acc.z += xv * w.z; acc.w += xv * w.w;
    }
    float di = dinv[nn];
    int pl = f4 >> 3;
    int qin = (2 * f4) & 15;
    __half2* base = hs + pl * PL_H2 + (nn << 4);
    base[qin]     = __floats2half2_rn(acc.x * di, acc.y * di);
    base[qin + 1] = __floats2half2_rn(acc.z * di, acc.w * di);
}

// ---------------- pass0 gather: plane0 (features 0..31) -> act0 fp16 ----------------
__global__ __launch_bounds__(512) void k_gp0(const int* __restrict__ row_ptr,
                                             const int* __restrict__ col,
                                             const __half2* __restrict__ hp,   // plane0 [n][16]
                                             const float* __restrict__ dinv,
                                             const float* __restrict__ bias,   // uses [0:32]
                                             unsigned int* __restrict__ act0,  // [n][16] half2-as-uint
                                             int n) {
    const int t = threadIdx.x;
    const int lane = t & 63, wid = t >> 6;
    const int g = lane >> 4, fl = lane & 15;
    const int d = (blockIdx.x << 3) + wid;
    if (d >= n) return;
    const int beg = row_ptr[d], end = row_ptr[d + 1];
    float2 acc = make_float2(0.f, 0.f);
    if (g == 0) acc = __half22float2(hp[(d << 4) + fl]);   // self loop
    int e = beg;
    for (; e + 15 < end; e += 16) {
        int s0 = __builtin_nontemporal_load(col + e + g);
        int s1 = __builtin_nontemporal_load(col + e + 4 + g);
        int s2 = __builtin_nontemporal_load(col + e + 8 + g);
        int s3 = __builtin_nontemporal_load(col + e + 12 + g);
        float2 v0 = __half22float2(hp[(s0 << 4) + fl]);
        float2 v1 = __half22float2(hp[(s1 << 4) + fl]);
        float2 v2 = __half22float2(hp[(s2 << 4) + fl]);
        float2 v3 = __half22float2(hp[(s3 << 4) + fl]);
        acc.x += (v0.x + v1.x) + (v2.x + v3.x);
        acc.y += (v0.y + v1.y) + (v2.y + v3.y);
    }
    for (; e < end; e += 4) {
        int i = e + g;
        if (i < end) {
            int s = __builtin_nontemporal_load(col + i);
            float2 v = __half22float2(hp[(s << 4) + fl]);
            acc.x += v.x; acc.y += v.y;
        }
    }
    acc.x += __shfl_xor(acc.x, 16, 64); acc.y += __shfl_xor(acc.y, 16, 64);
    acc.x += __shfl_xor(acc.x, 32, 64); acc.y += __shfl_xor(acc.y, 32, 64);
    if (g == 0) {
        float di = dinv[d];
        float2 bb = ((const float2*)bias)[fl];
        float vx = acc.x * di + bb.x;
        float vy = acc.y * di + bb.y;
        vx = vx > 0.f ? vx : NEG_SLOPE_C * vx;
        vy = vy > 0.f ? vy : NEG_SLOPE_C * vy;
        __half2 h = __floats2half2_rn(vx, vy);
        __builtin_nontemporal_store(__builtin_bit_cast(unsigned int, h), act0 + (d << 4) + fl);
    }
}

// ---------------- pass1 gather + full-row assembly + fdot2 transform -> next hs planes ----------------
__global__ __launch_bounds__(512) void k_gp1T(const int* __restrict__ row_ptr,
                                              const int* __restrict__ col,
                                              const __half2* __restrict__ hp,   // plane1 [n][16]
                                              const unsigned int* __restrict__ act0,
                                              const float* __restrict__ dinv,
                                              const float* __restrict__ bias,   // uses [32:64]
                                              const uint4* __restrict__ wh,     // pre-packed fp16 W
                                              __half* __restrict__ hnext,       // 2-plane base
                                              int n) {
    __shared__ uint4 WhL[8 * HID_C];
    __shared__ __half2 rowh[8][32];
    const int t = threadIdx.x;
    WhL[t] = wh[t];
    __syncthreads();

    const int lane = t & 63, wid = t >> 6;
    const int g = lane >> 4, fl = lane & 15;
    const int d = (blockIdx.x << 3) + wid;
    if (d >= n) return;
    const int beg = row_ptr[d], end = row_ptr[d + 1];
    float2 acc = make_float2(0.f, 0.f);
    if (g == 0) acc = __half22float2(hp[(d << 4) + fl]);
    int e = beg;
    for (; e + 15 < end; e += 16) {
        int s0 = __builtin_nontemporal_load(col + e + g);
        int s1 = __builtin_nontemporal_load(col + e + 4 + g);
        int s2 = __builtin_nontemporal_load(col + e + 8 + g);
        int s3 = __builtin_nontemporal_load(col + e + 12 + g);
        float2 v0 = __half22float2(hp[(s0 << 4) + fl]);
        float2 v1 = __half22float2(hp[(s1 << 4) + fl]);
        float2 v2 = __half22float2(hp[(s2 << 4) + fl]);
        float2 v3 = __half22float2(hp[(s3 << 4) + fl]);
        acc.x += (v0.x + v1.x) + (v2.x + v3.x);
        acc.y += (v0.y + v1.y) + (v2.y + v3.y);
    }
    for (; e < end; e += 4) {
        int i = e + g;
        if (i < end) {
            int s = __builtin_nontemporal_load(col + i);
            float2 v = __half22float2(hp[(s << 4) + fl]);
            acc.x += v.x; acc.y += v.y;
        }
    }
    acc.x += __shfl_xor(acc.x, 16, 64); acc.y += __shfl_xor(acc.y, 16, 64);
    acc.x += __shfl_xor(acc.x, 32, 64); acc.y += __shfl_xor(acc.y, 32, 64);

    const float di = dinv[d];
    if (lane < 16)   // stage features 0..31 from act0
        rowh[wid][lane] = __builtin_bit_cast(__half2, __builtin_nontemporal_load(act0 + (d << 4) + lane));
    if (g == 0) {    // epilogue for features 32..63
        float2 bb = ((const float2*)bias)[16 + fl];
        float vx = acc.x * di + bb.x;
        float vy = acc.y * di + bb.y;
        vx = vx > 0.f ? vx : NEG_SLOPE_C * vx;
        vy = vy > 0.f ? vy : NEG_SLOPE_C * vy;
        rowh[wid][16 + fl] = __floats2half2_rn(vx, vy);
    }
    // wave-synchronous LDS read-back; fdot2 transform
    float s = 0.f;
    const uint4* rq = (const uint4*)rowh[wid];
#pragma unroll
    for (int k8 = 0; k8 < 8; ++k8) {
        uint4 wv = WhL[(k8 << 6) + lane];
        uint4 rv = rq[k8];
        s = fdot2(rv.x, wv.x, s);
        s = fdot2(rv.y, wv.y, s);
        s = fdot2(rv.z, wv.z, s);
        s = fdot2(rv.w, wv.w, s);
    }
    int pl = lane >> 5, fi = lane & 31;
    hnext[(size_t)pl * (N_NODES_C * 32) + d * 32 + fi] = __float2half(s * di);
}

// ---------------- pass1 gather + full-row assembly + final FC -> out ----------------
__global__ __launch_bounds__(512) void k_gpF(const int* __restrict__ row_ptr,
                                             const int* __restrict__ col,
                                             const __half2* __restrict__ hp,   // plane1
                                             const unsigned int* __restrict__ act0,
                                             const float* __restrict__ dinv,
                                             const float* __restrict__ bias,   // uses [32:64]
                                             const float2* __restrict__ wf2,   // [32][10] k2-pairs
                                             const float* __restrict__ bn,
                                             float* __restrict__ out, int n) {
    __shared__ float2 Wf2[32 * N_CLS_C];
    __shared__ float bL[N_CLS_C];
    __shared__ float2 rowf[8][32];
    const int t = threadIdx.x;
    if (t < 32 * N_CLS_C) Wf2[t] = wf2[t];
    if (t < N_CLS_C) bL[t] = bn[t];
    __syncthreads();

    const int lane = t & 63, wid = t >> 6;
    const int g = lane >> 4, fl = lane & 15;
    const int d = (blockIdx.x << 3) + wid;
    if (d >= n) return;
    const int beg = row_ptr[d], end = row_ptr[d + 1];
    float2 acc = make_float2(0.f, 0.f);
    if (g == 0) acc = __half22float2(hp[(d << 4) + fl]);
    int e = beg;
    for (; e + 15 < end; e += 16) {
        int s0 = __builtin_nontemporal_load(col + e + g);
        int s1 = __builtin_nontemporal_load(col + e + 4 + g);
        int s2 = __builtin_nontemporal_load(col + e + 8 + g);
        int s3 = __builtin_nontemporal_load(col + e + 12 + g);
        float2 v0 = __half22float2(hp[(s0 << 4) + fl]);
        float2 v1 = __half22float2(hp[(s1 << 4) + fl]);
        float2 v2 = __half22float2(hp[(s2 << 4) + fl]);
        float2 v3 = __half22float2(hp[(s3 << 4) + fl]);
        acc.x += (v0.x + v1.x) + (v2.x + v3.x);
        acc.y += (v0.y + v1.y) + (v2.y + v3.y);
    }
    for (; e < end; e += 4) {
        int i = e + g;
        if (i < end) {
            int s = __builtin_nontemporal_load(col + i);
            float2 v = __half22float2(hp[(s << 4) + fl]);
            acc.x += v.x; acc.y += v.y;
        }
    }
    acc.x += __shfl_xor(acc.x, 16, 64); acc.y += __shfl_xor(acc.y, 16, 64);
    acc.x += __shfl_xor(acc.x, 32, 64); acc.y += __shfl_xor(acc.y, 32, 64);

    const float di = dinv[d];
    if (lane < 16) {
        __half2 h = __builtin_bit_cast(__half2, __builtin_nontemporal_load(act0 + (d << 4) + lane));
        rowf[wid][lane] = __half22float2(h);
    }
    if (g == 0) {
        float2 bb = ((const float2*)bias)[16 + fl];
        float vx = acc.x * di + bb.x;
        float vy = acc.y * di + bb.y;
        vx = vx > 0.f ? vx : NEG_SLOPE_C * vx;
        vy = vy > 0.f ? vy : NEG_SLOPE_C * vy;
        rowf[wid][16 + fl] = make_float2(vx, vy);
    }
    if (lane < N_CLS_C) {
        float s = bL[lane];
#pragma unroll
        for (int k2 = 0; k2 < 32; ++k2) {
            float2 a = rowf[wid][k2];
            float2 w = Wf2[k2 * N_CLS_C + lane];
            s += a.x * w.x + a.y * w.y;
        }
        out[d * N_CLS_C + lane] = s;
    }
}

extern "C" void kernel_launch(void* const* d_in, const int* in_sizes, int n_in,
                              void* d_out, int out_size, void* d_ws, size_t ws_size,
                              hipStream_t stream) {
    const float* x   = (const float*)d_in[0];
    const int*   ei  = (const int*)d_in[1];
    const float* W1  = (const float*)d_in[2];
    const float* b1  = (const float*)d_in[3];
    const float* W2  = (const float*)d_in[4];
    const float* b2  = (const float*)d_in[5];
    const float* W3  = (const float*)d_in[6];
    const float* b3  = (const float*)d_in[7];
    const float* Wfc = (const float*)d_in[8];
    const float* bfc = (const float*)d_in[9];
    float* out = (float*)d_out;

    const int N = N_NODES_C;
    const int E = N_EDGES_C;
    const int* src = ei;
    const int* dst = ei + E;

    // workspace carve-up (16B aligned)
    float*  dinv    = (float*)d_ws;                   // N
    int*    bcur    = (int*)(dinv + N);               // 128 (zeroed by k_prep)
    int*    row_ptr = bcur + 128;                     // N+4
    uint4*  wh2     = (uint4*)(row_ptr + N + 4);      // 512
    uint4*  wh3     = wh2 + 512;                      // 512
    float2* wf2     = (float2*)(wh3 + 512);           // 320 (pad 320)
    int*    col     = (int*)(wf2 + 320);              // E
    int*    pairs   = col + E;                        // NBUCK*BCAP ints (14.45 MB)
    __half* hsA     = (__half*)pairs;                 // 2 planes, N*64 halves (aliases pairs)
    __half* hsB     = (__half*)(pairs + (size_t)NBUCK * BCAP);   // 2 planes
    unsigned int* act0 = (unsigned int*)(hsB + (size_t)N * HID_C); // N*16 uints (6.4 MB)

    int gN8 = (N + 7) / 8;                            // 12500
    int gM0 = (N * 16 + 255) / 256;                   // 6250
    int gBK = (E + TILE - 1) / TILE;                  // 1563

    __half2* hsA0 = (__half2*)hsA;
    __half2* hsA1 = hsA0 + PL_H2;
    __half2* hsB0 = (__half2*)hsB;
    __half2* hsB1 = hsB0 + PL_H2;

    // ---- prepack + zero ----
    k_prep<<<4, 256, 0, stream>>>(W2, W3, Wfc, wh2, wh3, wf2, bcur);

    // ---- CSR build (+ dinv) ----
    k_bucket<<<gBK, 256, 0, stream>>>(src, dst, bcur, pairs, E);
    k_build<<<NBUCK, 1024, 0, stream>>>(pairs, bcur, row_ptr, dinv, col);

    // ---- layer 1 transform ----
    k_mm0<<<gM0, 256, 0, stream>>>(x, W1, dinv, (__half2*)hsA, N);

    // ---- layer 1: two-pass gather + fused transform ----
    k_gp0 <<<gN8, 512, 0, stream>>>(row_ptr, col, hsA0, dinv, b1, act0, N);
    k_gp1T<<<gN8, 512, 0, stream>>>(row_ptr, col, hsA1, act0, dinv, b1, wh2, hsB, N);
    // ---- layer 2 ----
    k_gp0 <<<gN8, 512, 0, stream>>>(row_ptr, col, hsB0, dinv, b2, act0, N);
    k_gp1T<<<gN8, 512, 0, stream>>>(row_ptr, col, hsB1, act0, dinv, b2, wh3, hsA, N);
    // ---- layer 3: pass0 + final FC ----
    k_gp0 <<<gN8, 512, 0, stream>>>(row_ptr, col, hsA0, dinv, b3, act0, N);
    k_gpF <<<gN8, 512, 0, stream>>>(row_ptr, col, hsA1, act0, dinv, b3, wf2, bfc, out, N);
}

// Round 17
// 403.081 us; speedup vs baseline: 1.4971x; 1.4971x over previous
//
#include <hip/hip_runtime.h>
#include <hip/hip_fp16.h>

#define N_NODES_C 100000
#define N_EDGES_C 3200000
#define IN_F_C 10
#define HID_C 64
#define N_CLS_C 10
#define NEG_SLOPE_C 0.01f

#define NBUCK 98
#define BCAP  36864
#define TILE  2048

typedef _Float16 f16x2 __attribute__((ext_vector_type(2)));

__device__ __forceinline__ float fdot2(unsigned int a, unsigned int b, float c) {
#if defined(__has_builtin) && __has_builtin(__builtin_amdgcn_fdot2)
    return __builtin_amdgcn_fdot2(__builtin_bit_cast(f16x2, a), __builtin_bit_cast(f16x2, b), c, false);
#else
    __half2 ah = __builtin_bit_cast(__half2, a), bh = __builtin_bit_cast(__half2, b);
    float2 af = __half22float2(ah), bf = __half22float2(bh);
    return c + af.x * bf.x + af.y * bf.y;
#endif
}

// ---------------- prepack + bcur zero ----------------
__global__ __launch_bounds__(256) void k_prep(const float* __restrict__ W2, const float* __restrict__ W3,
                                              const float* __restrict__ Wfc,
                                              uint4* __restrict__ wh2, uint4* __restrict__ wh3,
                                              float4* __restrict__ wfq, int* __restrict__ bcur) {
    const int b = blockIdx.x, t = threadIdx.x;
    if (b < 2) {
        const float* W = b ? W3 : W2;
        uint4* wh = b ? wh3 : wh2;
        for (int i = t; i < 8 * HID_C; i += 256) {
            int k8 = i >> 6, f = i & 63;
            __half2 h[4];
#pragma unroll
            for (int j = 0; j < 4; ++j)
                h[j] = __floats2half2_rn(W[(8 * k8 + 2 * j) * HID_C + f],
                                         W[(8 * k8 + 2 * j + 1) * HID_C + f]);
            wh[i] = *(uint4*)h;
        }
    } else if (b == 2) {
        if (t < 16 * N_CLS_C) {
            int k4 = t / N_CLS_C, f = t - k4 * N_CLS_C;
            wfq[t] = make_float4(Wfc[(4 * k4 + 0) * N_CLS_C + f], Wfc[(4 * k4 + 1) * N_CLS_C + f],
                                 Wfc[(4 * k4 + 2) * N_CLS_C + f], Wfc[(4 * k4 + 3) * N_CLS_C + f]);
        }
    } else {
        if (t < 128) bcur[t] = 0;
    }
}

// ---------------- pass 1: bucket partition (proven) ----------------
__global__ __launch_bounds__(256) void k_bucket(const int* __restrict__ src,
                                                const int* __restrict__ dst,
                                                int* __restrict__ bcur,
                                                int* __restrict__ pairs, int E) {
    __shared__ int lcnt[NBUCK];
    __shared__ int gbase[NBUCK];
    const int t = threadIdx.x;
    for (int i = t; i < NBUCK; i += 256) lcnt[i] = 0;
    __syncthreads();
    const int base = blockIdx.x * TILE;
    int p[8], r[8], nb[8];
#pragma unroll
    for (int i = 0; i < 8; ++i) {
        int e = base + t + i * 256;
        if (e < E) {
            int s = src[e], d = dst[e];
            int b = d >> 10;
            nb[i] = b;
            p[i] = (s << 10) | (d & 1023);
            r[i] = atomicAdd(&lcnt[b], 1);
        }
    }
    __syncthreads();
    for (int i = t; i < NBUCK; i += 256)
        gbase[i] = lcnt[i] ? atomicAdd(&bcur[i], lcnt[i]) : 0;
    __syncthreads();
#pragma unroll
    for (int i = 0; i < 8; ++i) {
        int e = base + t + i * 256;
        if (e < E) {
            int pos = gbase[nb[i]] + r[i];
            if (pos < BCAP) pairs[nb[i] * BCAP + pos] = p[i];
        }
    }
}

// ---------------- pass 2: per-bucket build, bucket-prefix fused (proven) ----------------
__global__ __launch_bounds__(1024) void k_build(const int* __restrict__ pairs,
                                                const int* __restrict__ bcur,
                                                int* __restrict__ row_ptr,
                                                float* __restrict__ dinv,
                                                int* __restrict__ col) {
    __shared__ int hist[1024];
    __shared__ int sm[1024];
    __shared__ int bs[128];
    const int b = blockIdx.x;
    const int t = threadIdx.x;
    const int n = min(bcur[b], BCAP);
    const int* pp = pairs + b * BCAP;

    if (t < 128) bs[t] = (t < NBUCK) ? bcur[t] : 0;
    __syncthreads();
    for (int off = 1; off < 128; off <<= 1) {
        int u = 0;
        if (t < 128 && t >= off) u = bs[t - off];
        __syncthreads();
        if (t < 128) bs[t] += u;
        __syncthreads();
    }
    const int base = (b > 0) ? bs[b - 1] : 0;

    hist[t] = 0;
    __syncthreads();
    for (int i = t; i < n; i += 1024) atomicAdd(&hist[pp[i] & 1023], 1);
    __syncthreads();
    int c = hist[t];
    sm[t] = c;
    __syncthreads();
    for (int off = 1; off < 1024; off <<= 1) {
        int u = (t >= off) ? sm[t - off] : 0;
        __syncthreads();
        sm[t] += u;
        __syncthreads();
    }
    int rp = base + sm[t] - c;
    int gnode = (b << 10) + t;
    if (gnode < N_NODES_C) {
        row_ptr[gnode] = rp;
        dinv[gnode] = rsqrtf((float)(c + 1));
        if (gnode == N_NODES_C - 1) row_ptr[N_NODES_C] = rp + c;
    }
    __syncthreads();
    sm[t] = rp;
    __syncthreads();
    for (int i = t; i < n; i += 1024) {
        int p = pp[i];
        int idx = atomicAdd(&sm[p & 1023], 1);
        col[idx] = p >> 10;
    }
}

// ---------------- layer-1 transform (proven) ----------------
__global__ __launch_bounds__(256) void k_mm0(const float* __restrict__ x,
                                             const float* __restrict__ W,
                                             const float* __restrict__ dinv,
                                             __half* __restrict__ hs, int n) {
    __shared__ float4 W4[IN_F_C * 16];
    const int t = threadIdx.x;
    for (int i = t; i < IN_F_C * 16; i += 256) {
        int k = i >> 4, f4 = i & 15;
        W4[i] = ((const float4*)(W + k * HID_C))[f4];
    }
    __syncthreads();
    int idx = blockIdx.x * 256 + t;
    if (idx >= n * 16) return;
    int nn = idx >> 4, f4 = idx & 15;
    const float* row = x + nn * IN_F_C;
    float4 acc = make_float4(0.f, 0.f, 0.f, 0.f);
#pragma unroll
    for (int k = 0; k < IN_F_C; ++k) {
        float xv = row[k];
        float4 w = W4[k * 16 + f4];
        acc.x += xv * w.x; acc.y += xv * w.y; acc.z += xv * w.z; acc.w += xv * w.w;
    }
    float di = dinv[nn];
    ((__half2*)hs)[(nn << 5) + 2 * f4]     = __floats2half2_rn(acc.x * di, acc.y * di);
    ((__half2*)hs)[(nn << 5) + 2 * f4 + 1] = __floats2half2_rn(acc.z * di, acc.w * di);
}

// 16-edge batch accumulate into acc (float4), cursor e
#define GBATCH(e, acc)                                                                 \
    {                                                                                  \
        int s0 = col[(e) + g], s1 = col[(e) + 4 + g];                                  \
        int s2 = col[(e) + 8 + g], s3 = col[(e) + 12 + g];                             \
        float2 r0 = hsv[(s0 << 4) + fl], r1 = hsv[(s1 << 4) + fl];                     \
        float2 r2 = hsv[(s2 << 4) + fl], r3 = hsv[(s3 << 4) + fl];                     \
        float2 x0 = __half22float2(*(__half2*)&r0.x), x1 = __half22float2(*(__half2*)&r0.y); \
        float2 y0 = __half22float2(*(__half2*)&r1.x), y1 = __half22float2(*(__half2*)&r1.y); \
        float2 z0 = __half22float2(*(__half2*)&r2.x), z1 = __half22float2(*(__half2*)&r2.y); \
        float2 w0 = __half22float2(*(__half2*)&r3.x), w1 = __half22float2(*(__half2*)&r3.y); \
        acc.x += (x0.x + y0.x) + (z0.x + w0.x);                                        \
        acc.y += (x0.y + y0.y) + (z0.y + w0.y);                                        \
        acc.z += (x1.x + y1.x) + (z1.x + w1.x);                                        \
        acc.w += (x1.y + y1.y) + (z1.y + w1.y);                                        \
    }

// joint dual-row batch: 8 col loads, then 8 independent hs loads in flight
#define GBATCH2(e0, e1, acc0, acc1)                                                    \
    {                                                                                  \
        int a0 = col[(e0) + g], a1 = col[(e0) + 4 + g];                                \
        int a2 = col[(e0) + 8 + g], a3 = col[(e0) + 12 + g];                           \
        int b0 = col[(e1) + g], b1 = col[(e1) + 4 + g];                                \
        int b2 = col[(e1) + 8 + g], b3 = col[(e1) + 12 + g];                           \
        float2 r0 = hsv[(a0 << 4) + fl], r1 = hsv[(a1 << 4) + fl];                     \
        float2 r2 = hsv[(a2 << 4) + fl], r3 = hsv[(a3 << 4) + fl];                     \
        float2 q0 = hsv[(b0 << 4) + fl], q1 = hsv[(b1 << 4) + fl];                     \
        float2 q2 = hsv[(b2 << 4) + fl], q3 = hsv[(b3 << 4) + fl];                     \
        float2 x0 = __half22float2(*(__half2*)&r0.x), x1 = __half22float2(*(__half2*)&r0.y); \
        float2 y0 = __half22float2(*(__half2*)&r1.x), y1 = __half22float2(*(__half2*)&r1.y); \
        float2 z0 = __half22float2(*(__half2*)&r2.x), z1 = __half22float2(*(__half2*)&r2.y); \
        float2 w0 = __half22float2(*(__half2*)&r3.x), w1 = __half22float2(*(__half2*)&r3.y); \
        acc0.x += (x0.x + y0.x) + (z0.x + w0.x);                                       \
        acc0.y += (x0.y + y0.y) + (z0.y + w0.y);                                       \
        acc0.z += (x1.x + y1.x) + (z1.x + w1.x);                                       \
        acc0.w += (x1.y + y1.y) + (z1.y + w1.y);                                       \
        x0 = __half22float2(*(__half2*)&q0.x); x1 = __half22float2(*(__half2*)&q0.y);  \
        y0 = __half22float2(*(__half2*)&q1.x); y1 = __half22float2(*(__half2*)&q1.y);  \
        z0 = __half22float2(*(__half2*)&q2.x); z1 = __half22float2(*(__half2*)&q2.y);  \
        w0 = __half22float2(*(__half2*)&q3.x); w1 = __half22float2(*(__half2*)&q3.y);  \
        acc1.x += (x0.x + y0.x) + (z0.x + w0.x);                                       \
        acc1.y += (x0.y + y0.y) + (z0.y + w0.y);                                       \
        acc1.z += (x1.x + y1.x) + (z1.x + w1.x);                                       \
        acc1.w += (x1.y + y1.y) + (z1.y + w1.y);                                       \
    }

#define GTAIL(e, endv, acc)                                                            \
    for (; (e) < (endv); (e) += 4) {                                                   \
        int i = (e) + g;                                                               \
        if (i < (endv)) {                                                              \
            float2 r = hsv[(col[i] << 4) + fl];                                        \
            float2 u0 = __half22float2(*(__half2*)&r.x);                               \
            float2 u1 = __half22float2(*(__half2*)&r.y);                               \
            acc.x += u0.x; acc.y += u0.y; acc.z += u1.x; acc.w += u1.y;                \
        }                                                                              \
    }

#define GREDUCE(acc)                                                                   \
    acc.x += __shfl_xor(acc.x, 16, 64); acc.y += __shfl_xor(acc.y, 16, 64);            \
    acc.z += __shfl_xor(acc.z, 16, 64); acc.w += __shfl_xor(acc.w, 16, 64);            \
    acc.x += __shfl_xor(acc.x, 32, 64); acc.y += __shfl_xor(acc.y, 32, 64);            \
    acc.z += __shfl_xor(acc.z, 32, 64); acc.w += __shfl_xor(acc.w, 32, 64);

#define GSELF(d, acc)                                                                  \
    if (g == 0 && (d) < n) {                                                           \
        float2 raw = hsv[((d) << 4) + fl];                                             \
        float2 l0 = __half22float2(*(__half2*)&raw.x);                                 \
        float2 l1 = __half22float2(*(__half2*)&raw.y);                                 \
        acc = make_float4(l0.x, l0.y, l1.x, l1.y);                                     \
    }

// ---------------- fused: dual-row gather + epilogue + fdot2 transform ----------------
__global__ __launch_bounds__(512) void k_gft(const int* __restrict__ row_ptr,
                                             const int* __restrict__ col,
                                             const __half* __restrict__ hsrc,
                                             const float* __restrict__ dinv,
                                             const float* __restrict__ bias,
                                             const uint4* __restrict__ wh,
                                             __half* __restrict__ hnext, int n) {
    __shared__ uint4 WhL[8 * HID_C];
    __shared__ __half2 rowh[8][32];
    const int t = threadIdx.x;
    WhL[t] = wh[t];
    __syncthreads();

    const int lane = t & 63, wid = t >> 6;
    const int g = lane >> 4, fl = lane & 15;
    const int d0 = (blockIdx.x << 4) + wid;
    const int d1 = d0 + 8;
    const float2* hsv = (const float2*)hsrc;

    int e0 = 0, end0 = -1, e1 = 0, end1 = -1;
    if (d0 < n) { e0 = row_ptr[d0]; end0 = row_ptr[d0 + 1]; }
    if (d1 < n) { e1 = row_ptr[d1]; end1 = row_ptr[d1 + 1]; }

    float4 acc0 = make_float4(0.f, 0.f, 0.f, 0.f), acc1 = acc0;
    GSELF(d0, acc0)
    GSELF(d1, acc1)

    while (e0 + 15 < end0 && e1 + 15 < end1) {
        GBATCH2(e0, e1, acc0, acc1)
        e0 += 16; e1 += 16;
    }
    for (; e0 + 15 < end0; e0 += 16) GBATCH(e0, acc0)
    for (; e1 + 15 < end1; e1 += 16) GBATCH(e1, acc1)
    GTAIL(e0, end0, acc0)
    GTAIL(e1, end1, acc1)
    GREDUCE(acc0)
    GREDUCE(acc1)

    // epilogue + transform, row 0 then row 1 (wave-synchronous LDS reuse)
#define EPI_XFORM(d, acc)                                                              \
    if ((d) < n) {                                                                     \
        const float di = dinv[d];                                                      \
        if (g == 0) {                                                                  \
            float4 bb = ((const float4*)bias)[fl];                                     \
            float4 v;                                                                  \
            v.x = acc.x * di + bb.x; v.y = acc.y * di + bb.y;                          \
            v.z = acc.z * di + bb.z; v.w = acc.w * di + bb.w;                          \
            v.x = v.x > 0.f ? v.x : NEG_SLOPE_C * v.x;                                 \
            v.y = v.y > 0.f ? v.y : NEG_SLOPE_C * v.y;                                 \
            v.z = v.z > 0.f ? v.z : NEG_SLOPE_C * v.z;                                 \
            v.w = v.w > 0.f ? v.w : NEG_SLOPE_C * v.w;                                 \
            rowh[wid][2 * fl]     = __floats2half2_rn(v.x, v.y);                       \
            rowh[wid][2 * fl + 1] = __floats2half2_rn(v.z, v.w);                       \
        }                                                                              \
        float s = 0.f;                                                                 \
        const uint4* rq = (const uint4*)rowh[wid];                                     \
        _Pragma("unroll")                                                              \
        for (int k8 = 0; k8 < 8; ++k8) {                                               \
            uint4 wv = WhL[(k8 << 6) + lane];                                          \
            uint4 rv = rq[k8];                                                         \
            s = fdot2(rv.x, wv.x, s);                                                  \
            s = fdot2(rv.y, wv.y, s);                                                  \
            s = fdot2(rv.z, wv.z, s);                                                  \
            s = fdot2(rv.w, wv.w, s);                                                  \
        }                                                                              \
        hnext[((d) << 6) + lane] = __float2half(s * di);                               \
    }

    EPI_XFORM(d0, acc0)
    EPI_XFORM(d1, acc1)
#undef EPI_XFORM
}

// ---------------- fused: dual-row gather + epilogue + final FC ----------------
__global__ __launch_bounds__(512) void k_gfc(const int* __restrict__ row_ptr,
                                             const int* __restrict__ col,
                                             const __half* __restrict__ hsrc,
                                             const float* __restrict__ dinv,
                                             const float* __restrict__ bias,
                                             const float4* __restrict__ wq,
                                             const float* __restrict__ bn,
                                             float* __restrict__ out, int n) {
    __shared__ float4 Ws4[16 * N_CLS_C];
    __shared__ float rowbuf[8][64];
    const int t = threadIdx.x;
    if (t < 16 * N_CLS_C) Ws4[t] = wq[t];
    __syncthreads();

    const int lane = t & 63, wid = t >> 6;
    const int g = lane >> 4, fl = lane & 15;
    const int d0 = (blockIdx.x << 4) + wid;
    const int d1 = d0 + 8;
    const float2* hsv = (const float2*)hsrc;

    int e0 = 0, end0 = -1, e1 = 0, end1 = -1;
    if (d0 < n) { e0 = row_ptr[d0]; end0 = row_ptr[d0 + 1]; }
    if (d1 < n) { e1 = row_ptr[d1]; end1 = row_ptr[d1 + 1]; }

    float4 acc0 = make_float4(0.f, 0.f, 0.f, 0.f), acc1 = acc0;
    GSELF(d0, acc0)
    GSELF(d1, acc1)

    while (e0 + 15 < end0 && e1 + 15 < end1) {
        GBATCH2(e0, e1, acc0, acc1)
        e0 += 16; e1 += 16;
    }
    for (; e0 + 15 < end0; e0 += 16) GBATCH(e0, acc0)
    for (; e1 + 15 < end1; e1 += 16) GBATCH(e1, acc1)
    GTAIL(e0, end0, acc0)
    GTAIL(e1, end1, acc1)
    GREDUCE(acc0)
    GREDUCE(acc1)

#define EPI_FC(d, acc)                                                                 \
    if ((d) < n) {                                                                     \
        const float di = dinv[d];                                                      \
        if (g == 0) {                                                                  \
            float4 bb = ((const float4*)bias)[fl];                                     \
            float4 v;                                                                  \
            v.x = acc.x * di + bb.x; v.y = acc.y * di + bb.y;                          \
            v.z = acc.z * di + bb.z; v.w = acc.w * di + bb.w;                          \
            v.x = v.x > 0.f ? v.x : NEG_SLOPE_C * v.x;                                 \
            v.y = v.y > 0.f ? v.y : NEG_SLOPE_C * v.y;                                 \
            v.z = v.z > 0.f ? v.z : NEG_SLOPE_C * v.z;                                 \
            v.w = v.w > 0.f ? v.w : NEG_SLOPE_C * v.w;                                 \
            ((float4*)rowbuf[wid])[fl] = v;                                            \
        }                                                                              \
        if (lane < N_CLS_C) {                                                          \
            float s = bn[lane];                                                        \
            const float4* rb = (const float4*)rowbuf[wid];                             \
            _Pragma("unroll")                                                          \
            for (int k4 = 0; k4 < 16; ++k4) {                                          \
                float4 r4 = rb[k4];                                                    \
                float4 w4 = Ws4[k4 * N_CLS_C + lane];                                  \
                s += r4.x * w4.x + r4.y * w4.y + r4.z * w4.z + r4.w * w4.w;            \
            }                                                                          \
            out[(d) * N_CLS_C + lane] = s;                                             \
        }                                                                              \
    }

    EPI_FC(d0, acc0)
    EPI_FC(d1, acc1)
#undef EPI_FC
}

extern "C" void kernel_launch(void* const* d_in, const int* in_sizes, int n_in,
                              void* d_out, int out_size, void* d_ws, size_t ws_size,
                              hipStream_t stream) {
    const float* x   = (const float*)d_in[0];
    const int*   ei  = (const int*)d_in[1];
    const float* W1  = (const float*)d_in[2];
    const float* b1  = (const float*)d_in[3];
    const float* W2  = (const float*)d_in[4];
    const float* b2  = (const float*)d_in[5];
    const float* W3  = (const float*)d_in[6];
    const float* b3  = (const float*)d_in[7];
    const float* Wfc = (const float*)d_in[8];
    const float* bfc = (const float*)d_in[9];
    float* out = (float*)d_out;

    const int N = N_NODES_C;
    const int E = N_EDGES_C;
    const int* src = ei;
    const int* dst = ei + E;

    // workspace carve-up (16B aligned)
    float*  dinv    = (float*)d_ws;                   // N
    int*    bcur    = (int*)(dinv + N);               // 128 (zeroed by k_prep)
    int*    row_ptr = bcur + 128;                     // N+4
    uint4*  wh2     = (uint4*)(row_ptr + N + 4);      // 512
    uint4*  wh3     = wh2 + 512;                      // 512
    float4* wfcq    = (float4*)(wh3 + 512);           // 160
    int*    col     = (int*)(wfcq + 160);             // E
    int*    pairs   = col + E;                        // NBUCK*BCAP ints
    __half* hsA     = (__half*)pairs;                 // N*64 halves (aliases pairs)
    __half* hsB     = (__half*)(pairs + (size_t)NBUCK * BCAP);

    int gN16 = (N + 15) / 16;                         // 6250
    int gM0  = (N * 16 + 255) / 256;                  // 6250
    int gBK  = (E + TILE - 1) / TILE;                 // 1563

    // ---- prepack + zero ----
    k_prep<<<4, 256, 0, stream>>>(W2, W3, Wfc, wh2, wh3, wfcq, bcur);

    // ---- CSR build (+ dinv) ----
    k_bucket<<<gBK, 256, 0, stream>>>(src, dst, bcur, pairs, E);
    k_build<<<NBUCK, 1024, 0, stream>>>(pairs, bcur, row_ptr, dinv, col);

    // ---- layer 1 transform ----
    k_mm0<<<gM0, 256, 0, stream>>>(x, W1, dinv, hsA, N);

    // ---- fused dual-row gather + transform chain ----
    k_gft<<<gN16, 512, 0, stream>>>(row_ptr, col, hsA, dinv, b1, wh2, hsB, N);
    k_gft<<<gN16, 512, 0, stream>>>(row_ptr, col, hsB, dinv, b2, wh3, hsA, N);
    k_gfc<<<gN16, 512, 0, stream>>>(row_ptr, col, hsA, dinv, b3, wfcq, bfc, out, N);
}

// Round 18
// 401.318 us; speedup vs baseline: 1.5037x; 1.0044x over previous
//
#include <hip/hip_runtime.h>
#include <hip/hip_fp16.h>

#define N_NODES_C 100000
#define N_EDGES_C 3200000
#define IN_F_C 10
#define HID_C 64
#define N_CLS_C 10
#define NEG_SLOPE_C 0.01f

#define NBUCK 98
#define BCAP  36864
#define TILE  2048

typedef _Float16 f16x2 __attribute__((ext_vector_type(2)));

__device__ __forceinline__ float fdot2(unsigned int a, unsigned int b, float c) {
#if defined(__has_builtin) && __has_builtin(__builtin_amdgcn_fdot2)
    return __builtin_amdgcn_fdot2(__builtin_bit_cast(f16x2, a), __builtin_bit_cast(f16x2, b), c, false);
#else
    __half2 ah = __builtin_bit_cast(__half2, a), bh = __builtin_bit_cast(__half2, b);
    float2 af = __half22float2(ah), bf = __half22float2(bh);
    return c + af.x * bf.x + af.y * bf.y;
#endif
}

// ---------------- prepack + bcur zero ----------------
__global__ __launch_bounds__(256) void k_prep(const float* __restrict__ W2, const float* __restrict__ W3,
                                              const float* __restrict__ Wfc,
                                              uint4* __restrict__ wh2, uint4* __restrict__ wh3,
                                              float4* __restrict__ wfq, int* __restrict__ bcur) {
    const int b = blockIdx.x, t = threadIdx.x;
    if (b < 2) {
        const float* W = b ? W3 : W2;
        uint4* wh = b ? wh3 : wh2;
        for (int i = t; i < 8 * HID_C; i += 256) {
            int k8 = i >> 6, f = i & 63;
            __half2 h[4];
#pragma unroll
            for (int j = 0; j < 4; ++j)
                h[j] = __floats2half2_rn(W[(8 * k8 + 2 * j) * HID_C + f],
                                         W[(8 * k8 + 2 * j + 1) * HID_C + f]);
            wh[i] = *(uint4*)h;
        }
    } else if (b == 2) {
        if (t < 16 * N_CLS_C) {
            int k4 = t / N_CLS_C, f = t - k4 * N_CLS_C;
            wfq[t] = make_float4(Wfc[(4 * k4 + 0) * N_CLS_C + f], Wfc[(4 * k4 + 1) * N_CLS_C + f],
                                 Wfc[(4 * k4 + 2) * N_CLS_C + f], Wfc[(4 * k4 + 3) * N_CLS_C + f]);
        }
    } else {
        if (t < 128) bcur[t] = 0;
    }
}

// ---------------- pass 1: bucket partition, per-wave lcnt (conflict-reduced) ----------------
__global__ __launch_bounds__(256) void k_bucket(const int* __restrict__ src,
                                                const int* __restrict__ dst,
                                                int* __restrict__ bcur,
                                                int* __restrict__ pairs, int E) {
    __shared__ int lcnt[4][NBUCK];
    __shared__ int wb[4][NBUCK];
    const int t = threadIdx.x;
    const int w = t >> 6;
    for (int i = t; i < 4 * NBUCK; i += 256) ((int*)lcnt)[i] = 0;
    __syncthreads();
    const int base = blockIdx.x * TILE;
    int p[8], r[8], nb[8];
#pragma unroll
    for (int i = 0; i < 8; ++i) {
        int e = base + t + i * 256;
        if (e < E) {
            int s = src[e], d = dst[e];
            int b = d >> 10;
            nb[i] = b;
            p[i] = (s << 10) | (d & 1023);
            r[i] = atomicAdd(&lcnt[w][b], 1);   // per-wave counter: no inter-wave serialization
        }
    }
    __syncthreads();
    for (int i = t; i < NBUCK; i += 256) {
        int c0 = lcnt[0][i], c1 = lcnt[1][i], c2 = lcnt[2][i], c3 = lcnt[3][i];
        int tot = c0 + c1 + c2 + c3;
        int gb = tot ? atomicAdd(&bcur[i], tot) : 0;
        wb[0][i] = gb; wb[1][i] = gb + c0; wb[2][i] = gb + c0 + c1; wb[3][i] = gb + c0 + c1 + c2;
    }
    __syncthreads();
#pragma unroll
    for (int i = 0; i < 8; ++i) {
        int e = base + t + i * 256;
        if (e < E) {
            int pos = wb[w][nb[i]] + r[i];
            if (pos < BCAP) pairs[nb[i] * BCAP + pos] = p[i];
        }
    }
}

// ---------------- pass 2: per-bucket build, bucket-prefix fused (proven) ----------------
__global__ __launch_bounds__(1024) void k_build(const int* __restrict__ pairs,
                                                const int* __restrict__ bcur,
                                                int* __restrict__ row_ptr,
                                                float* __restrict__ dinv,
                                                int* __restrict__ col) {
    __shared__ int hist[1024];
    __shared__ int sm[1024];
    __shared__ int bs[128];
    const int b = blockIdx.x;
    const int t = threadIdx.x;
    const int n = min(bcur[b], BCAP);
    const int* pp = pairs + b * BCAP;

    if (t < 128) bs[t] = (t < NBUCK) ? bcur[t] : 0;
    __syncthreads();
    for (int off = 1; off < 128; off <<= 1) {
        int u = 0;
        if (t < 128 && t >= off) u = bs[t - off];
        __syncthreads();
        if (t < 128) bs[t] += u;
        __syncthreads();
    }
    const int base = (b > 0) ? bs[b - 1] : 0;

    hist[t] = 0;
    __syncthreads();
    for (int i = t; i < n; i += 1024) atomicAdd(&hist[pp[i] & 1023], 1);
    __syncthreads();
    int c = hist[t];
    sm[t] = c;
    __syncthreads();
    for (int off = 1; off < 1024; off <<= 1) {
        int u = (t >= off) ? sm[t - off] : 0;
        __syncthreads();
        sm[t] += u;
        __syncthreads();
    }
    int rp = base + sm[t] - c;
    int gnode = (b << 10) + t;
    if (gnode < N_NODES_C) {
        row_ptr[gnode] = rp;
        dinv[gnode] = rsqrtf((float)(c + 1));
        if (gnode == N_NODES_C - 1) row_ptr[N_NODES_C] = rp + c;
    }
    __syncthreads();
    sm[t] = rp;
    __syncthreads();
    for (int i = t; i < n; i += 1024) {
        int p = pp[i];
        int idx = atomicAdd(&sm[p & 1023], 1);
        col[idx] = p >> 10;
    }
}

// ---------------- layer-1 transform (proven) ----------------
__global__ __launch_bounds__(256) void k_mm0(const float* __restrict__ x,
                                             const float* __restrict__ W,
                                             const float* __restrict__ dinv,
                                             __half* __restrict__ hs, int n) {
    __shared__ float4 W4[IN_F_C * 16];
    const int t = threadIdx.x;
    for (int i = t; i < IN_F_C * 16; i += 256) {
        int k = i >> 4, f4 = i & 15;
        W4[i] = ((const float4*)(W + k * HID_C))[f4];
    }
    __syncthreads();
    int idx = blockIdx.x * 256 + t;
    if (idx >= n * 16) return;
    int nn = idx >> 4, f4 = idx & 15;
    const float* row = x + nn * IN_F_C;
    float4 acc = make_float4(0.f, 0.f, 0.f, 0.f);
#pragma unroll
    for (int k = 0; k < IN_F_C; ++k) {
        float xv = row[k];
        float4 w = W4[k * 16 + f4];
        acc.x += xv * w.x; acc.y += xv * w.y; acc.z += xv * w.z; acc.w += xv * w.w;
    }
    float di = dinv[nn];
    ((__half2*)hs)[(nn << 5) + 2 * f4]     = __floats2half2_rn(acc.x * di, acc.y * di);
    ((__half2*)hs)[(nn << 5) + 2 * f4 + 1] = __floats2half2_rn(acc.z * di, acc.w * di);
}

// accumulate one uint4 (8 halves) into accA/accB
#define ACC8(q)                                                                        \
    {                                                                                  \
        const __half2* hp_ = (const __half2*)&(q);                                     \
        float2 a0_ = __half22float2(hp_[0]), a1_ = __half22float2(hp_[1]);             \
        float2 a2_ = __half22float2(hp_[2]), a3_ = __half22float2(hp_[3]);             \
        accA.x += a0_.x; accA.y += a0_.y; accA.z += a1_.x; accA.w += a1_.y;            \
        accB.x += a2_.x; accB.y += a2_.y; accB.z += a3_.x; accB.w += a3_.y;            \
    }

// gather core: 8 lanes/edge x 16B; 2 hsv wave-instructions per 16 edges
#define GCORE()                                                                        \
    float4 accA = make_float4(0.f, 0.f, 0.f, 0.f), accB = accA;                        \
    if (g8 == 0 && d < n) { uint4 q_ = hsq[(d << 3) + f8]; ACC8(q_) }                  \
    int e = 0, end = -1;                                                               \
    if (d < n) { e = row_ptr[d]; end = row_ptr[d + 1]; }                               \
    for (; e + 15 < end; e += 16) {                                                    \
        int s0_ = __builtin_nontemporal_load(col + e + g8);                            \
        int s1_ = __builtin_nontemporal_load(col + e + 8 + g8);                        \
        uint4 q0_ = hsq[(s0_ << 3) + f8];                                              \
        uint4 q1_ = hsq[(s1_ << 3) + f8];                                              \
        ACC8(q0_)                                                                      \
        ACC8(q1_)                                                                      \
    }                                                                                  \
    for (; e < end; e += 8) {                                                          \
        int i_ = e + g8;                                                               \
        if (i_ < end) {                                                                \
            int s_ = __builtin_nontemporal_load(col + i_);                             \
            uint4 q_ = hsq[(s_ << 3) + f8];                                            \
            ACC8(q_)                                                                   \
        }                                                                              \
    }                                                                                  \
    accA.x += __shfl_xor(accA.x, 8, 64);  accA.y += __shfl_xor(accA.y, 8, 64);         \
    accA.z += __shfl_xor(accA.z, 8, 64);  accA.w += __shfl_xor(accA.w, 8, 64);         \
    accB.x += __shfl_xor(accB.x, 8, 64);  accB.y += __shfl_xor(accB.y, 8, 64);         \
    accB.z += __shfl_xor(accB.z, 8, 64);  accB.w += __shfl_xor(accB.w, 8, 64);         \
    accA.x += __shfl_xor(accA.x, 16, 64); accA.y += __shfl_xor(accA.y, 16, 64);        \
    accA.z += __shfl_xor(accA.z, 16, 64); accA.w += __shfl_xor(accA.w, 16, 64);        \
    accB.x += __shfl_xor(accB.x, 16, 64); accB.y += __shfl_xor(accB.y, 16, 64);        \
    accB.z += __shfl_xor(accB.z, 16, 64); accB.w += __shfl_xor(accB.w, 16, 64);        \
    accA.x += __shfl_xor(accA.x, 32, 64); accA.y += __shfl_xor(accA.y, 32, 64);        \
    accA.z += __shfl_xor(accA.z, 32, 64); accA.w += __shfl_xor(accA.w, 32, 64);        \
    accB.x += __shfl_xor(accB.x, 32, 64); accB.y += __shfl_xor(accB.y, 32, 64);        \
    accB.z += __shfl_xor(accB.z, 32, 64); accB.w += __shfl_xor(accB.w, 32, 64);

// epilogue math: v = lrelu(acc*di + bias[8*f8 .. 8*f8+7])
#define EPI_MATH()                                                                     \
    const float4 bb0 = ((const float4*)bias)[2 * f8];                                  \
    const float4 bb1 = ((const float4*)bias)[2 * f8 + 1];                              \
    float4 v0, v1;                                                                     \
    v0.x = accA.x * di + bb0.x; v0.y = accA.y * di + bb0.y;                            \
    v0.z = accA.z * di + bb0.z; v0.w = accA.w * di + bb0.w;                            \
    v1.x = accB.x * di + bb1.x; v1.y = accB.y * di + bb1.y;                            \
    v1.z = accB.z * di + bb1.z; v1.w = accB.w * di + bb1.w;                            \
    v0.x = v0.x > 0.f ? v0.x : NEG_SLOPE_C * v0.x;                                     \
    v0.y = v0.y > 0.f ? v0.y : NEG_SLOPE_C * v0.y;                                     \
    v0.z = v0.z > 0.f ? v0.z : NEG_SLOPE_C * v0.z;                                     \
    v0.w = v0.w > 0.f ? v0.w : NEG_SLOPE_C * v0.w;                                     \
    v1.x = v1.x > 0.f ? v1.x : NEG_SLOPE_C * v1.x;                                     \
    v1.y = v1.y > 0.f ? v1.y : NEG_SLOPE_C * v1.y;                                     \
    v1.z = v1.z > 0.f ? v1.z : NEG_SLOPE_C * v1.z;                                     \
    v1.w = v1.w > 0.f ? v1.w : NEG_SLOPE_C * v1.w;

// ---------------- fused: uint4 gather + epilogue + fdot2 transform ----------------
__global__ __launch_bounds__(512) void k_gft(const int* __restrict__ row_ptr,
                                             const int* __restrict__ col,
                                             const __half* __restrict__ hsrc,
                                             const float* __restrict__ dinv,
                                             const float* __restrict__ bias,
                                             const uint4* __restrict__ wh,
                                             __half* __restrict__ hnext, int n) {
    __shared__ uint4 WhL[8 * HID_C];
    __shared__ uint4 rowq[8][8];
    const int t = threadIdx.x;
    WhL[t] = wh[t];
    __syncthreads();

    const int lane = t & 63, wid = t >> 6;
    const int g8 = lane >> 3, f8 = lane & 7;
    const int d = (blockIdx.x << 3) + wid;
    const uint4* hsq = (const uint4*)hsrc;     // 8 uint4 per row

    GCORE()
    if (d >= n) return;
    const float di = dinv[d];
    if (g8 == 0) {
        EPI_MATH()
        __half2 h[4];
        h[0] = __floats2half2_rn(v0.x, v0.y);
        h[1] = __floats2half2_rn(v0.z, v0.w);
        h[2] = __floats2half2_rn(v1.x, v1.y);
        h[3] = __floats2half2_rn(v1.z, v1.w);
        rowq[wid][f8] = *(uint4*)h;
    }
    // wave-synchronous LDS read-back; fdot2 transform
    float s = 0.f;
    const uint4* rq = rowq[wid];
#pragma unroll
    for (int k8 = 0; k8 < 8; ++k8) {
        uint4 wv = WhL[(k8 << 6) + lane];
        uint4 rv = rq[k8];
        s = fdot2(rv.x, wv.x, s);
        s = fdot2(rv.y, wv.y, s);
        s = fdot2(rv.z, wv.z, s);
        s = fdot2(rv.w, wv.w, s);
    }
    hnext[(d << 6) + lane] = __float2half(s * di);
}

// ---------------- fused: uint4 gather + epilogue + final FC ----------------
__global__ __launch_bounds__(512) void k_gfc(const int* __restrict__ row_ptr,
                                             const int* __restrict__ col,
                                             const __half* __restrict__ hsrc,
                                             const float* __restrict__ dinv,
                                             const float* __restrict__ bias,
                                             const float4* __restrict__ wq,
                                             const float* __restrict__ bn,
                                             float* __restrict__ out, int n) {
    __shared__ float4 Ws4[16 * N_CLS_C];
    __shared__ float rowbuf[8][64];
    const int t = threadIdx.x;
    if (t < 16 * N_CLS_C) Ws4[t] = wq[t];
    __syncthreads();

    const int lane = t & 63, wid = t >> 6;
    const int g8 = lane >> 3, f8 = lane & 7;
    const int d = (blockIdx.x << 3) + wid;
    const uint4* hsq = (const uint4*)hsrc;

    GCORE()
    if (d >= n) return;
    const float di = dinv[d];
    if (g8 == 0) {
        EPI_MATH()
        ((float4*)rowbuf[wid])[2 * f8]     = v0;
        ((float4*)rowbuf[wid])[2 * f8 + 1] = v1;
    }
    if (lane < N_CLS_C) {
        float s = bn[lane];
        const float4* rb = (const float4*)rowbuf[wid];
#pragma unroll
        for (int k4 = 0; k4 < 16; ++k4) {
            float4 r4 = rb[k4];
            float4 w4 = Ws4[k4 * N_CLS_C + lane];
            s += r4.x * w4.x + r4.y * w4.y + r4.z * w4.z + r4.w * w4.w;
        }
        out[d * N_CLS_C + lane] = s;
    }
}

extern "C" void kernel_launch(void* const* d_in, const int* in_sizes, int n_in,
                              void* d_out, int out_size, void* d_ws, size_t ws_size,
                              hipStream_t stream) {
    const float* x   = (const float*)d_in[0];
    const int*   ei  = (const int*)d_in[1];
    const float* W1  = (const float*)d_in[2];
    const float* b1  = (const float*)d_in[3];
    const float* W2  = (const float*)d_in[4];
    const float* b2  = (const float*)d_in[5];
    const float* W3  = (const float*)d_in[6];
    const float* b3  = (const float*)d_in[7];
    const float* Wfc = (const float*)d_in[8];
    const float* bfc = (const float*)d_in[9];
    float* out = (float*)d_out;

    const int N = N_NODES_C;
    const int E = N_EDGES_C;
    const int* src = ei;
    const int* dst = ei + E;

    // workspace carve-up (16B aligned)
    float*  dinv    = (float*)d_ws;                   // N
    int*    bcur    = (int*)(dinv + N);               // 128 (zeroed by k_prep)
    int*    row_ptr = bcur + 128;                     // N+4
    uint4*  wh2     = (uint4*)(row_ptr + N + 4);      // 512
    uint4*  wh3     = wh2 + 512;                      // 512
    float4* wfcq    = (float4*)(wh3 + 512);           // 160
    int*    col     = (int*)(wfcq + 160);             // E
    int*    pairs   = col + E;                        // NBUCK*BCAP ints
    __half* hsA     = (__half*)pairs;                 // N*64 halves (aliases pairs)
    __half* hsB     = (__half*)(pairs + (size_t)NBUCK * BCAP);

    int gN8 = (N + 7) / 8;                            // 12500
    int gM0 = (N * 16 + 255) / 256;                   // 6250
    int gBK = (E + TILE - 1) / TILE;                  // 1563

    // ---- prepack + zero ----
    k_prep<<<4, 256, 0, stream>>>(W2, W3, Wfc, wh2, wh3, wfcq, bcur);

    // ---- CSR build (+ dinv) ----
    k_bucket<<<gBK, 256, 0, stream>>>(src, dst, bcur, pairs, E);
    k_build<<<NBUCK, 1024, 0, stream>>>(pairs, bcur, row_ptr, dinv, col);

    // ---- layer 1 transform ----
    k_mm0<<<gM0, 256, 0, stream>>>(x, W1, dinv, hsA, N);

    // ---- fused uint4 gather + transform chain ----
    k_gft<<<gN8, 512, 0, stream>>>(row_ptr, col, hsA, dinv, b1, wh2, hsB, N);
    k_gft<<<gN8, 512, 0, stream>>>(row_ptr, col, hsB, dinv, b2, wh3, hsA, N);
    k_gfc<<<gN8, 512, 0, stream>>>(row_ptr, col, hsA, dinv, b3, wfcq, bfc, out, N);
}